// Round 1
// baseline (1021.507 us; speedup 1.0000x reference)
//
#include <hip/hip_runtime.h>
#include <hip/hip_fp16.h>
#include <cstdint>
#include <cstddef>

#define B_   4
#define T_   4096
#define D_   2560
#define H_   10
#define BW   256
#define NROWS (B_*T_)   // 16384
#define CCH  32         // number of chunks along T
#define LCH  128        // chunk length (CCH*LCH == T_)

typedef short s16x8 __attribute__((ext_vector_type(8)));
typedef float f32x4 __attribute__((ext_vector_type(4)));

__device__ __forceinline__ unsigned short f2bf(float f) {
  union { float f; uint32_t u; } v; v.f = f;
  uint32_t u = v.u;
  u += 0x7fffu + ((u >> 16) & 1u);   // round-to-nearest-even
  return (unsigned short)(u >> 16);
}

// ---------------- prep: transpose+cast weights to bf16 [H][512][256] (n-major,
// k-contiguous, n<256 = ig cols, n>=256 = rg cols), and softplus(recurrent_param)
__global__ __launch_bounds__(256) void prep_kernel(
    const float* __restrict__ igw, const float* __restrict__ rgw,
    const float* __restrict__ rp,
    unsigned short* __restrict__ wt, float* __restrict__ sp) {
  int idx = blockIdx.x * 256 + threadIdx.x;
  const int total = H_ * 512 * 256;
  if (idx < total) {
    int k = idx & 255;
    int n = (idx >> 8) & 511;
    int h = idx >> 17;
    float w = (n < 256) ? igw[(h*BW + k)*BW + n]
                        : rgw[(h*BW + k)*BW + (n - 256)];
    wt[idx] = f2bf(w);
  }
  if (idx < D_) {
    float z = rp[idx];
    sp[idx] = fmaxf(z, 0.0f) + log1pf(__expf(-fabsf(z)));
  }
}

// ---------------- gates: block = 4 waves, tile = 64 rows x 512 cols (ig|rg), one head
// MFMA 16x16x32 bf16. A-frag: A[m=lane&15][k=quad*8+j]; B-frag: B[k=quad*8+j][n=lane&15];
// C/D: col=lane&15, row=quad*4+r.
__global__ __launch_bounds__(256) void gates_kernel(
    const float* __restrict__ act, const int* __restrict__ pos,
    const float* __restrict__ igb, const float* __restrict__ rgb,
    const unsigned short* __restrict__ wt, const float* __restrict__ sp,
    __half* __restrict__ la, __half* __restrict__ xn) {
  const int h    = blockIdx.y;
  const int wave = threadIdx.x >> 6;
  const int lane = threadIdx.x & 63;
  const int l15  = lane & 15;
  const int quad = lane >> 4;
  const int m0   = blockIdx.x * 64 + wave * 16;
  const int hd   = h * BW;

  f32x4 acc[32];
  #pragma unroll
  for (int q = 0; q < 32; ++q) acc[q] = (f32x4){0.f, 0.f, 0.f, 0.f};

  const float* arow = act + (size_t)(m0 + l15) * D_ + hd;
  const unsigned short* wth = wt + (size_t)h * 512 * 256;

  for (int kt = 0; kt < 8; ++kt) {
    const int koff = kt * 32 + quad * 8;
    f32x4 f0 = *(const f32x4*)(arow + koff);
    f32x4 f1 = *(const f32x4*)(arow + koff + 4);
    s16x8 afrag;
    afrag[0] = (short)f2bf(f0[0]); afrag[1] = (short)f2bf(f0[1]);
    afrag[2] = (short)f2bf(f0[2]); afrag[3] = (short)f2bf(f0[3]);
    afrag[4] = (short)f2bf(f1[0]); afrag[5] = (short)f2bf(f1[1]);
    afrag[6] = (short)f2bf(f1[2]); afrag[7] = (short)f2bf(f1[3]);
    #pragma unroll
    for (int q = 0; q < 32; ++q) {
      const s16x8 bfrag = *(const s16x8*)(wth + (size_t)(q*16 + l15) * 256 + koff);
      acc[q] = __builtin_amdgcn_mfma_f32_16x16x32_bf16(afrag, bfrag, acc[q], 0, 0, 0);
    }
  }

  // epilogue
  int  rowv[4];
  bool rst[4];
  #pragma unroll
  for (int r = 0; r < 4; ++r) {
    rowv[r] = m0 + quad * 4 + r;
    rst[r]  = (pos[rowv[r]] == 0);
  }
  #pragma unroll
  for (int q = 0; q < 16; ++q) {
    const int j = q * 16 + l15;
    const int d = hd + j;
    const float bi  = igb[d];
    const float br  = rgb[d];
    const float spd = sp[d];
    #pragma unroll
    for (int r = 0; r < 4; ++r) {
      const int row = rowv[r];
      const float ig_logit = acc[q][r]      + bi;
      const float rg_logit = acc[q + 16][r] + br;
      const float igate = 1.0f / (1.0f + __expf(-ig_logit));
      const float rgate = 1.0f / (1.0f + __expf(-rg_logit));
      const float loga  = -8.0f * rgate * spd;
      const float a     = __expf(loga);
      const float mult  = rst[r] ? 1.0f : sqrtf(fmaxf(1.0f - a * a, 0.0f));
      const float xv    = act[(size_t)row * D_ + d];
      const float xo    = xv * igate * mult;
      const size_t o = (size_t)row * D_ + d;
      la[o] = __float2half(rst[r] ? -60000.0f : loga);
      xn[o] = __float2half(xo);
    }
  }
}

// ---------------- scan phase A: per-chunk cumulative product + local scan
__global__ __launch_bounds__(256) void scanA_kernel(
    const __half* __restrict__ la, const __half* __restrict__ xn,
    float* __restrict__ Pb, float* __restrict__ Xb) {
  const int d = blockIdx.x * 256 + threadIdx.x;
  const int c = blockIdx.y;
  const int b = blockIdx.z;
  size_t base = ((size_t)b * T_ + (size_t)c * LCH) * D_ + d;
  float h = 0.f, P = 1.f;
  for (int t = 0; t < LCH; ++t) {
    const float a = __expf(__half2float(la[base]));  // reset rows: -60000 -> 0
    const float x = __half2float(xn[base]);
    h = fmaf(a, h, x);
    P *= a;
    base += D_;
  }
  const size_t o = ((size_t)b * CCH + c) * D_ + d;
  Pb[o] = P;
  Xb[o] = h;
}

// ---------------- scan phase B: inter-chunk carry scan (tiny)
__global__ __launch_bounds__(256) void scanB_kernel(
    const float* __restrict__ Pb, const float* __restrict__ Xb,
    float* __restrict__ H0) {
  const int d = blockIdx.x * 256 + threadIdx.x;
  const int b = blockIdx.y;
  float carry = 0.f;
  for (int c = 0; c < CCH; ++c) {
    const size_t o = ((size_t)b * CCH + c) * D_ + d;
    H0[o] = carry;
    carry = fmaf(Pb[o], carry, Xb[o]);
  }
}

// ---------------- scan phase C: replay chunk with carry-in, write output
__global__ __launch_bounds__(256) void scanC_kernel(
    const __half* __restrict__ la, const __half* __restrict__ xn,
    const float* __restrict__ H0, float* __restrict__ out) {
  const int d = blockIdx.x * 256 + threadIdx.x;
  const int c = blockIdx.y;
  const int b = blockIdx.z;
  size_t base = ((size_t)b * T_ + (size_t)c * LCH) * D_ + d;
  float h = H0[((size_t)b * CCH + c) * D_ + d];
  for (int t = 0; t < LCH; ++t) {
    const float a = __expf(__half2float(la[base]));
    const float x = __half2float(xn[base]);
    h = fmaf(a, h, x);
    out[base] = h;
    base += D_;
  }
}

extern "C" void kernel_launch(void* const* d_in, const int* in_sizes, int n_in,
                              void* d_out, int out_size, void* d_ws, size_t ws_size,
                              hipStream_t stream) {
  const float* act = (const float*)d_in[0];
  const int*   pos = (const int*)d_in[1];
  const float* igw = (const float*)d_in[2];
  const float* igb = (const float*)d_in[3];
  const float* rgw = (const float*)d_in[4];
  const float* rgb = (const float*)d_in[5];
  const float* rp  = (const float*)d_in[6];
  float* out = (float*)d_out;

  char* ws = (char*)d_ws;
  __half* la = (__half*)ws;                 ws += (size_t)B_ * T_ * D_ * 2;
  __half* xn = (__half*)ws;                 ws += (size_t)B_ * T_ * D_ * 2;
  unsigned short* wt = (unsigned short*)ws; ws += (size_t)H_ * 512 * 256 * 2;
  float* sp = (float*)ws;                   ws += 4096;                      // D_*4 padded
  float* Pb = (float*)ws;                   ws += (size_t)B_ * CCH * D_ * 4;
  float* Xb = (float*)ws;                   ws += (size_t)B_ * CCH * D_ * 4;
  float* H0 = (float*)ws;                   ws += (size_t)B_ * CCH * D_ * 4;

  prep_kernel<<<dim3((H_ * 512 * 256 + 255) / 256), 256, 0, stream>>>(igw, rgw, rp, wt, sp);
  gates_kernel<<<dim3(NROWS / 64, H_), 256, 0, stream>>>(act, pos, igb, rgb, wt, sp, la, xn);
  scanA_kernel<<<dim3(D_ / 256, CCH, B_), 256, 0, stream>>>(la, xn, Pb, Xb);
  scanB_kernel<<<dim3(D_ / 256, B_), 256, 0, stream>>>(Pb, Xb, H0);
  scanC_kernel<<<dim3(D_ / 256, CCH, B_), 256, 0, stream>>>(la, xn, H0, out);
}